// Round 1
// baseline (752.664 us; speedup 1.0000x reference)
//
#include <hip/hip_runtime.h>
#include <hip/hip_bf16.h>
#include <math.h>

#define GROUP 36
#define MANT 8
#define BM 128
#define BN 128
#define BK 32

typedef __attribute__((ext_vector_type(4))) float f32x4;
typedef __attribute__((ext_vector_type(8))) short bf16x8;

// ---------------- BFP quantize: fp32 -> bf16 (exact: <=8 significand bits) ----
__global__ void bfp_quant_kernel(const float* __restrict__ src,
                                 __hip_bfloat16* __restrict__ dst,
                                 int ngroups) {
    int g = blockIdx.x * blockDim.x + threadIdx.x;
    if (g >= ngroups) return;

    const float4* gp = reinterpret_cast<const float4*>(src + (size_t)g * GROUP);
    float4 v4[9];
#pragma unroll
    for (int i = 0; i < 9; ++i) v4[i] = gp[i];
    const float* v = reinterpret_cast<const float*>(v4);

    float amax = 0.0f;
#pragma unroll
    for (int i = 0; i < GROUP; ++i) amax = fmaxf(amax, fabsf(v[i]));

    __align__(16) __hip_bfloat16 outv[GROUP];
    if (amax > 0.0f) {
        int ex;
        (void)frexpf(amax, &ex);          // amax = f * 2^ex, f in [0.5,1)
        const int e = ex - 1;             // floor(log2(amax))
        const float step  = ldexpf(1.0f, e - (MANT - 1));   // 2^(e-7), exact
        const float rstep = ldexpf(1.0f, (MANT - 1) - e);   // 2^(7-e), exact
#pragma unroll
        for (int i = 0; i < GROUP; ++i) {
            float q = truncf(v[i] * rstep) * step;  // all steps exact in fp32
            outv[i] = __float2bfloat16(q);          // |t|<=255 -> exact in bf16
        }
    } else {
#pragma unroll
        for (int i = 0; i < GROUP; ++i) outv[i] = __float2bfloat16(v[i]); // all zeros
    }

    uint2* dp = reinterpret_cast<uint2*>(dst + (size_t)g * GROUP); // 72g bytes: 8B aligned
    const uint2* op = reinterpret_cast<const uint2*>(outv);
#pragma unroll
    for (int i = 0; i < 9; ++i) dp[i] = op[i];
}

// ---------------- bf16 MFMA GEMM: C[M][N] = A[M][K] * B[N][K]^T + bias[N] ----
// m97 structure: 128x128 tile, BK=32, 4 waves (2x2), 4x4 16x16x32 MFMA / wave,
// linear LDS + global_load_lds width 16, 2-barrier K-loop.
__global__ __launch_bounds__(256) void bfp_gemm_kernel(
    const __hip_bfloat16* __restrict__ A,
    const __hip_bfloat16* __restrict__ B,
    const float* __restrict__ bias,
    float* __restrict__ C,
    int M, int N, int K)
{
    __shared__ __align__(16) __hip_bfloat16 As[BM * BK];
    __shared__ __align__(16) __hip_bfloat16 Bs[BN * BK];

    const int tid  = threadIdx.x;
    const int lane = tid & 63;
    const int wave = tid >> 6;
    const int wm = wave >> 1, wn = wave & 1;

    // XCD-aware bijective swizzle (grid is a multiple of 8 here: 64*36=2304)
    const int nwg = gridDim.x;
    const int bid = blockIdx.x;
    int swz;
    if ((nwg & 7) == 0) {
        const int cpx = nwg >> 3;
        swz = (bid & 7) * cpx + (bid >> 3);
    } else {
        swz = bid;
    }
    const int ntn = N / BN;
    const int tm = swz / ntn;
    const int tn = swz % ntn;

    f32x4 acc[4][4];
#pragma unroll
    for (int i = 0; i < 4; ++i)
#pragma unroll
        for (int j = 0; j < 4; ++j) acc[i][j] = (f32x4){0.f, 0.f, 0.f, 0.f};

    const int lrow = lane & 15;   // fragment row (A) / col (B)
    const int kq   = lane >> 4;   // k-quad: 8 contiguous k per lane

    const int nk = K / BK;
    for (int t = 0; t < nk; ++t) {
        __syncthreads();  // previous tile's ds_reads done before overwrite
#pragma unroll
        for (int c = tid; c < (BM * BK) / 8; c += 256) {  // 512 x 16B chunks
            const int row  = c >> 2;
            const int col8 = c & 3;
            const __hip_bfloat16* ga = A + (size_t)(tm * BM + row) * K + t * BK + col8 * 8;
            __builtin_amdgcn_global_load_lds(
                (const __attribute__((address_space(1))) unsigned int*)ga,
                (__attribute__((address_space(3))) unsigned int*)(As + c * 8),
                16, 0, 0);
            const __hip_bfloat16* gb = B + (size_t)(tn * BN + row) * K + t * BK + col8 * 8;
            __builtin_amdgcn_global_load_lds(
                (const __attribute__((address_space(1))) unsigned int*)gb,
                (__attribute__((address_space(3))) unsigned int*)(Bs + c * 8),
                16, 0, 0);
        }
        __syncthreads();  // barrier drains vmcnt -> LDS tile ready

        bf16x8 a[4], b[4];
#pragma unroll
        for (int mi = 0; mi < 4; ++mi)
            a[mi] = *reinterpret_cast<const bf16x8*>(As + (wm * 64 + mi * 16 + lrow) * BK + kq * 8);
#pragma unroll
        for (int ni = 0; ni < 4; ++ni)
            b[ni] = *reinterpret_cast<const bf16x8*>(Bs + (wn * 64 + ni * 16 + lrow) * BK + kq * 8);

#pragma unroll
        for (int mi = 0; mi < 4; ++mi)
#pragma unroll
            for (int ni = 0; ni < 4; ++ni)
                acc[mi][ni] = __builtin_amdgcn_mfma_f32_16x16x32_bf16(
                    a[mi], b[ni], acc[mi][ni], 0, 0, 0);
    }

    // Epilogue: C/D mapping (m89-verified): col = lane&15, row = (lane>>4)*4 + j
#pragma unroll
    for (int mi = 0; mi < 4; ++mi) {
        const int rowb = tm * BM + wm * 64 + mi * 16 + kq * 4;
#pragma unroll
        for (int ni = 0; ni < 4; ++ni) {
            const int col = tn * BN + wn * 64 + ni * 16 + lrow;
            const float bb = bias[col];
            const f32x4 vv = acc[mi][ni];
#pragma unroll
            for (int j = 0; j < 4; ++j)
                C[(size_t)(rowb + j) * N + col] = vv[j] + bb;
        }
    }
}

extern "C" void kernel_launch(void* const* d_in, const int* in_sizes, int n_in,
                              void* d_out, int out_size, void* d_ws, size_t ws_size,
                              hipStream_t stream) {
    const float* inp  = (const float*)d_in[0];
    const float* wgt  = (const float*)d_in[1];
    const float* bias = (const float*)d_in[2];
    float* out = (float*)d_out;

    const int N = in_sizes[2];            // 4608
    const int K = in_sizes[1] / N;        // 4608
    const int M = in_sizes[0] / K;        // 8192

    __hip_bfloat16* qA = (__hip_bfloat16*)d_ws;
    __hip_bfloat16* qB = qA + (size_t)M * K;

    const int gA = (int)(((size_t)M * K) / GROUP);   // 1,048,576
    const int gB = (int)(((size_t)N * K) / GROUP);   //   589,824

    bfp_quant_kernel<<<(gA + 255) / 256, 256, 0, stream>>>(inp, qA, gA);
    bfp_quant_kernel<<<(gB + 255) / 256, 256, 0, stream>>>(wgt, qB, gB);

    const int grid = (M / BM) * (N / BN);            // 64*36 = 2304 (mult of 8)
    bfp_gemm_kernel<<<grid, 256, 0, stream>>>(qA, qB, bias, out, M, N, K);
}

// Round 2
// 744.457 us; speedup vs baseline: 1.0110x; 1.0110x over previous
//
#include <hip/hip_runtime.h>
#include <hip/hip_bf16.h>
#include <math.h>

#define GROUP 36
#define MANT 8
#define BM 128
#define BN 128
#define BK 32

typedef __attribute__((ext_vector_type(4))) float f32x4;
typedef __attribute__((ext_vector_type(8))) short bf16x8;

// ---------------- BFP quantize: fp32 -> bf16 (exact: <=8 significand bits) ----
// Coalesced via LDS: block stages 256 contiguous groups (36 KB) with stride-256
// float4 loads, each thread quantizes its own group out of LDS, packed bf16
// goes back through LDS for coalesced 16B stores.
__global__ __launch_bounds__(256) void bfp_quant_kernel(
    const float* __restrict__ src, __hip_bfloat16* __restrict__ dst, int ngroups)
{
    __shared__ __align__(16) float lds_f[256 * GROUP];   // 36 KB

    const int tid    = threadIdx.x;
    const int gbase  = blockIdx.x * 256;
    const int gcount = min(256, ngroups - gbase);
    if (gcount <= 0) return;

    // ---- stage global -> LDS, fully coalesced float4 ----
    const float4* gsrc = reinterpret_cast<const float4*>(src + (size_t)gbase * GROUP);
    float4* lf4 = reinterpret_cast<float4*>(lds_f);
    const int nv4 = gcount * (GROUP / 4);                // 9 float4 per group
    for (int i = tid; i < nv4; i += 256) lf4[i] = gsrc[i];
    __syncthreads();

    // ---- per-thread group quantize (registers) ----
    unsigned int out_pk[GROUP / 2];                      // 18 packed bf16x2
    const bool active = tid < gcount;
    if (active) {
        const float4* gp = reinterpret_cast<const float4*>(lds_f + tid * GROUP);
        float4 v4[9];
#pragma unroll
        for (int i = 0; i < 9; ++i) v4[i] = gp[i];
        const float* v = reinterpret_cast<const float*>(v4);

        float amax = 0.0f;
#pragma unroll
        for (int i = 0; i < GROUP; ++i) amax = fmaxf(amax, fabsf(v[i]));

        if (amax > 0.0f) {
            int ex;
            (void)frexpf(amax, &ex);          // amax = f * 2^ex, f in [0.5,1)
            const int e = ex - 1;             // floor(log2(amax))
            const float step  = ldexpf(1.0f, e - (MANT - 1));   // 2^(e-7), exact
            const float rstep = ldexpf(1.0f, (MANT - 1) - e);   // 2^(7-e), exact
#pragma unroll
            for (int i = 0; i < GROUP / 2; ++i) {
                float q0 = truncf(v[2 * i]     * rstep) * step;
                float q1 = truncf(v[2 * i + 1] * rstep) * step;
                unsigned int b0 = (unsigned int)__bfloat16_as_ushort(__float2bfloat16(q0));
                unsigned int b1 = (unsigned int)__bfloat16_as_ushort(__float2bfloat16(q1));
                out_pk[i] = b0 | (b1 << 16);
            }
        } else {
#pragma unroll
            for (int i = 0; i < GROUP / 2; ++i) {
                unsigned int b0 = (unsigned int)__bfloat16_as_ushort(__float2bfloat16(v[2 * i]));
                unsigned int b1 = (unsigned int)__bfloat16_as_ushort(__float2bfloat16(v[2 * i + 1]));
                out_pk[i] = b0 | (b1 << 16);
            }
        }
    }
    __syncthreads();   // everyone done READING float LDS before bf16 overwrite

    if (active) {
        unsigned int* lo = reinterpret_cast<unsigned int*>(lds_f) + tid * (GROUP / 2);
#pragma unroll
        for (int i = 0; i < GROUP / 2; ++i) lo[i] = out_pk[i];
    }
    __syncthreads();

    // ---- coalesced store LDS -> global (gcount*72 bytes) ----
    const unsigned int* lu = reinterpret_cast<const unsigned int*>(lds_f);
    unsigned int* gdst = reinterpret_cast<unsigned int*>(dst + (size_t)gbase * GROUP);
    const int nu  = gcount * (GROUP / 2);
    const int nu4 = nu >> 2;                             // full uint4 chunks
    const uint4* lu4 = reinterpret_cast<const uint4*>(lu);
    uint4* gd4 = reinterpret_cast<uint4*>(gdst);
    for (int i = tid; i < nu4; i += 256) gd4[i] = lu4[i];
    for (int i = (nu4 << 2) + tid; i < nu; i += 256) gdst[i] = lu[i];
}

// ---------------- bf16 MFMA GEMM: C[M][N] = A[M][K] * B[N][K]^T + bias[N] ----
// m97 structure: 128x128 tile, BK=32, 4 waves (2x2), 4x4 16x16x32 MFMA / wave,
// linear LDS + global_load_lds width 16, 2-barrier K-loop.
__global__ __launch_bounds__(256) void bfp_gemm_kernel(
    const __hip_bfloat16* __restrict__ A,
    const __hip_bfloat16* __restrict__ B,
    const float* __restrict__ bias,
    float* __restrict__ C,
    int M, int N, int K)
{
    __shared__ __align__(16) __hip_bfloat16 As[BM * BK];
    __shared__ __align__(16) __hip_bfloat16 Bs[BN * BK];

    const int tid  = threadIdx.x;
    const int lane = tid & 63;
    const int wave = tid >> 6;
    const int wm = wave >> 1, wn = wave & 1;

    // XCD-aware bijective swizzle (grid is a multiple of 8 here: 64*36=2304)
    const int nwg = gridDim.x;
    const int bid = blockIdx.x;
    int swz;
    if ((nwg & 7) == 0) {
        const int cpx = nwg >> 3;
        swz = (bid & 7) * cpx + (bid >> 3);
    } else {
        swz = bid;
    }
    const int ntn = N / BN;
    const int tm = swz / ntn;
    const int tn = swz % ntn;

    f32x4 acc[4][4];
#pragma unroll
    for (int i = 0; i < 4; ++i)
#pragma unroll
        for (int j = 0; j < 4; ++j) acc[i][j] = (f32x4){0.f, 0.f, 0.f, 0.f};

    const int lrow = lane & 15;   // fragment row (A) / col (B)
    const int kq   = lane >> 4;   // k-quad: 8 contiguous k per lane

    const int nk = K / BK;
    for (int t = 0; t < nk; ++t) {
        __syncthreads();  // previous tile's ds_reads done before overwrite
#pragma unroll
        for (int c = tid; c < (BM * BK) / 8; c += 256) {  // 512 x 16B chunks
            const int row  = c >> 2;
            const int col8 = c & 3;
            const __hip_bfloat16* ga = A + (size_t)(tm * BM + row) * K + t * BK + col8 * 8;
            __builtin_amdgcn_global_load_lds(
                (const __attribute__((address_space(1))) unsigned int*)ga,
                (__attribute__((address_space(3))) unsigned int*)(As + c * 8),
                16, 0, 0);
            const __hip_bfloat16* gb = B + (size_t)(tn * BN + row) * K + t * BK + col8 * 8;
            __builtin_amdgcn_global_load_lds(
                (const __attribute__((address_space(1))) unsigned int*)gb,
                (__attribute__((address_space(3))) unsigned int*)(Bs + c * 8),
                16, 0, 0);
        }
        __syncthreads();  // barrier drains vmcnt -> LDS tile ready

        bf16x8 a[4], b[4];
#pragma unroll
        for (int mi = 0; mi < 4; ++mi)
            a[mi] = *reinterpret_cast<const bf16x8*>(As + (wm * 64 + mi * 16 + lrow) * BK + kq * 8);
#pragma unroll
        for (int ni = 0; ni < 4; ++ni)
            b[ni] = *reinterpret_cast<const bf16x8*>(Bs + (wn * 64 + ni * 16 + lrow) * BK + kq * 8);

#pragma unroll
        for (int mi = 0; mi < 4; ++mi)
#pragma unroll
            for (int ni = 0; ni < 4; ++ni)
                acc[mi][ni] = __builtin_amdgcn_mfma_f32_16x16x32_bf16(
                    a[mi], b[ni], acc[mi][ni], 0, 0, 0);
    }

    // Epilogue: C/D mapping (m89-verified): col = lane&15, row = (lane>>4)*4 + j
#pragma unroll
    for (int mi = 0; mi < 4; ++mi) {
        const int rowb = tm * BM + wm * 64 + mi * 16 + kq * 4;
#pragma unroll
        for (int ni = 0; ni < 4; ++ni) {
            const int col = tn * BN + wn * 64 + ni * 16 + lrow;
            const float bb = bias[col];
            const f32x4 vv = acc[mi][ni];
#pragma unroll
            for (int j = 0; j < 4; ++j)
                C[(size_t)(rowb + j) * N + col] = vv[j] + bb;
        }
    }
}

extern "C" void kernel_launch(void* const* d_in, const int* in_sizes, int n_in,
                              void* d_out, int out_size, void* d_ws, size_t ws_size,
                              hipStream_t stream) {
    const float* inp  = (const float*)d_in[0];
    const float* wgt  = (const float*)d_in[1];
    const float* bias = (const float*)d_in[2];
    float* out = (float*)d_out;

    const int N = in_sizes[2];            // 4608
    const int K = in_sizes[1] / N;        // 4608
    const int M = in_sizes[0] / K;        // 8192

    __hip_bfloat16* qA = (__hip_bfloat16*)d_ws;
    __hip_bfloat16* qB = qA + (size_t)M * K;

    const int gA = (int)(((size_t)M * K) / GROUP);   // 1,048,576
    const int gB = (int)(((size_t)N * K) / GROUP);   //   589,824

    bfp_quant_kernel<<<(gA + 255) / 256, 256, 0, stream>>>(inp, qA, gA);
    bfp_quant_kernel<<<(gB + 255) / 256, 256, 0, stream>>>(wgt, qB, gB);

    const int grid = (M / BM) * (N / BN);            // 64*36 = 2304 (mult of 8)
    bfp_gemm_kernel<<<grid, 256, 0, stream>>>(qA, qB, bias, out, M, N, K);
}

// Round 4
// 667.794 us; speedup vs baseline: 1.1271x; 1.1148x over previous
//
#include <hip/hip_runtime.h>
#include <hip/hip_bf16.h>
#include <math.h>

#define GROUP 36
#define MANT 8

typedef __attribute__((ext_vector_type(4))) float f32x4;
typedef __attribute__((ext_vector_type(8))) short bf16x8;

// ---------------- BFP quantize: fp32 -> bf16 (exact: <=8 significand bits) ----
__global__ __launch_bounds__(256) void bfp_quant_kernel(
    const float* __restrict__ src, __hip_bfloat16* __restrict__ dst, int ngroups)
{
    __shared__ __align__(16) float lds_f[256 * GROUP];   // 36 KB

    const int tid    = threadIdx.x;
    const int gbase  = blockIdx.x * 256;
    const int gcount = min(256, ngroups - gbase);
    if (gcount <= 0) return;

    const float4* gsrc = reinterpret_cast<const float4*>(src + (size_t)gbase * GROUP);
    float4* lf4 = reinterpret_cast<float4*>(lds_f);
    const int nv4 = gcount * (GROUP / 4);
    for (int i = tid; i < nv4; i += 256) lf4[i] = gsrc[i];
    __syncthreads();

    unsigned int out_pk[GROUP / 2];
    const bool active = tid < gcount;
    if (active) {
        const float4* gp = reinterpret_cast<const float4*>(lds_f + tid * GROUP);
        float4 v4[9];
#pragma unroll
        for (int i = 0; i < 9; ++i) v4[i] = gp[i];
        const float* v = reinterpret_cast<const float*>(v4);

        float amax = 0.0f;
#pragma unroll
        for (int i = 0; i < GROUP; ++i) amax = fmaxf(amax, fabsf(v[i]));

        if (amax > 0.0f) {
            int ex;
            (void)frexpf(amax, &ex);
            const int e = ex - 1;                               // floor(log2(amax))
            const float step  = ldexpf(1.0f, e - (MANT - 1));   // 2^(e-7), exact
            const float rstep = ldexpf(1.0f, (MANT - 1) - e);   // 2^(7-e), exact
#pragma unroll
            for (int i = 0; i < GROUP / 2; ++i) {
                float q0 = truncf(v[2 * i]     * rstep) * step;
                float q1 = truncf(v[2 * i + 1] * rstep) * step;
                unsigned int b0 = (unsigned int)__bfloat16_as_ushort(__float2bfloat16(q0));
                unsigned int b1 = (unsigned int)__bfloat16_as_ushort(__float2bfloat16(q1));
                out_pk[i] = b0 | (b1 << 16);
            }
        } else {
#pragma unroll
            for (int i = 0; i < GROUP / 2; ++i) {
                unsigned int b0 = (unsigned int)__bfloat16_as_ushort(__float2bfloat16(v[2 * i]));
                unsigned int b1 = (unsigned int)__bfloat16_as_ushort(__float2bfloat16(v[2 * i + 1]));
                out_pk[i] = b0 | (b1 << 16);
            }
        }
    }
    __syncthreads();

    if (active) {
        unsigned int* lo = reinterpret_cast<unsigned int*>(lds_f) + tid * (GROUP / 2);
#pragma unroll
        for (int i = 0; i < GROUP / 2; ++i) lo[i] = out_pk[i];
    }
    __syncthreads();

    const unsigned int* lu = reinterpret_cast<const unsigned int*>(lds_f);
    unsigned int* gdst = reinterpret_cast<unsigned int*>(dst + (size_t)gbase * GROUP);
    const int nu  = gcount * (GROUP / 2);
    const int nu4 = nu >> 2;
    const uint4* lu4 = reinterpret_cast<const uint4*>(lu);
    uint4* gd4 = reinterpret_cast<uint4*>(gdst);
    for (int i = tid; i < nu4; i += 256) gd4[i] = lu4[i];
    for (int i = (nu4 << 2) + tid; i < nu; i += 256) gdst[i] = lu[i];
}

// ---------------- 256x256 8-phase bf16 MFMA GEMM: C = A * B^T + bias ----------
// 512 threads = 8 waves (2M x 4N). BK=64. LDS 128 KiB (2 buffers x (A,B) x 256x64).
// T2 granule-XOR swizzle: LDS physical granule pg at row r holds logical granule
// pg ^ (r&7); applied via pre-swizzled GLOBAL source (linear global_load_lds dest)
// + XOR on ds_read address (rule #21: both-sides-or-neither).
// Hazard ledger: tile t reads buf(t&1); all stages during tile t write buf^1,
// whose readers (tile t-1) drained before t-1's end barrier. One vmcnt(0)+barrier
// per tile; newest stage (B1) issued 2 phases before the wait.
// Gray-code quadrant order (0,0)->(0,1)->(1,1)->(1,0): 24 ds_read_b128/wave/tile.
#define BM 256
#define BN 256
#define BK 64
#define HALF_ELEMS (128 * 64)
#define TILE_ELEMS (256 * 64)

__device__ __forceinline__ void stage_half(const __hip_bfloat16* rowbase, int K,
                                           __hip_bfloat16* lhalf, int tid) {
    const int srcg = (tid & 7) ^ ((tid >> 3) & 7);   // pre-swizzled source granule
#pragma unroll
    for (int l = 0; l < 2; ++l) {
        const int s   = l * 512 + tid;               // linear 16B slot in half-tile
        const int row = s >> 3;                      // 0..127 (row&7 == (tid>>3)&7)
        const __hip_bfloat16* g = rowbase + (size_t)row * K + srcg * 8;
        __builtin_amdgcn_global_load_lds(
            (const __attribute__((address_space(1))) unsigned int*)g,
            (__attribute__((address_space(3))) unsigned int*)(lhalf + s * 8),
            16, 0, 0);
    }
}

#define BAR() do { __builtin_amdgcn_sched_barrier(0); \
                   __builtin_amdgcn_s_barrier();      \
                   __builtin_amdgcn_sched_barrier(0); } while (0)

#define READ_A(qr_) do {                                                        \
    _Pragma("unroll") for (int mi2 = 0; mi2 < 4; ++mi2) {                       \
        const int hrow = (qr_) * 64 + mi2 * 16 + fr;                            \
        _Pragma("unroll") for (int kk = 0; kk < 2; ++kk) {                      \
            const int pg = (kk * 4 + kq) ^ f7;                                  \
            a[mi2][kk] = *reinterpret_cast<const bf16x8*>(Ah + hrow * 64 + pg * 8); \
        } } } while (0)

#define READ_B(dst_, qc_) do {                                                  \
    _Pragma("unroll") for (int ni2 = 0; ni2 < 2; ++ni2) {                       \
        const int hrow = bro + (qc_) * 32 + ni2 * 16 + fr;                      \
        _Pragma("unroll") for (int kk = 0; kk < 2; ++kk) {                      \
            const int pg = (kk * 4 + kq) ^ f7;                                  \
            dst_[ni2][kk] = *reinterpret_cast<const bf16x8*>(Bh + hrow * 64 + pg * 8); \
        } } } while (0)

#define MFMA_QUAD(qr_, qc_, bb_) do {                                           \
    __builtin_amdgcn_s_setprio(1);                                              \
    _Pragma("unroll") for (int mi2 = 0; mi2 < 4; ++mi2)                         \
    _Pragma("unroll") for (int ni2 = 0; ni2 < 2; ++ni2)                         \
    _Pragma("unroll") for (int kk = 0; kk < 2; ++kk)                            \
        acc[(qr_) * 4 + mi2][(qc_) * 2 + ni2] =                                 \
            __builtin_amdgcn_mfma_f32_16x16x32_bf16(                            \
                a[mi2][kk], bb_[ni2][kk],                                       \
                acc[(qr_) * 4 + mi2][(qc_) * 2 + ni2], 0, 0, 0);                \
    __builtin_amdgcn_s_setprio(0); } while (0)

__global__ __launch_bounds__(512, 2) void bfp_gemm_kernel(
    const __hip_bfloat16* __restrict__ A,
    const __hip_bfloat16* __restrict__ B,
    const float* __restrict__ bias,
    float* __restrict__ C,
    int M, int N, int K)
{
    __shared__ __align__(16) __hip_bfloat16 lds[4 * TILE_ELEMS];  // 128 KiB

    __hip_bfloat16* As0 = lds;
    __hip_bfloat16* As1 = lds + TILE_ELEMS;
    __hip_bfloat16* Bs0 = lds + 2 * TILE_ELEMS;
    __hip_bfloat16* Bs1 = lds + 3 * TILE_ELEMS;

    const int tid  = threadIdx.x;
    const int lane = tid & 63;
    const int wave = tid >> 6;
    const int wm = wave >> 2;        // 0..1 -> rows wm*128
    const int wn = wave & 3;         // 0..3 -> cols wn*64

    // XCD-aware swizzle (grid = 576, multiple of 8)
    const int nwg = gridDim.x;
    const int bid = blockIdx.x;
    int swz;
    if ((nwg & 7) == 0) { swz = (bid & 7) * (nwg >> 3) + (bid >> 3); }
    else { swz = bid; }
    const int ntn = N / BN;
    const int tm = swz / ntn;
    const int tn = swz % ntn;

    const __hip_bfloat16* Abase = A + (size_t)(tm * BM) * K;
    const __hip_bfloat16* Bbase = B + (size_t)(tn * BN) * K;

    const int fr = lane & 15;        // fragment row within 16
    const int kq = lane >> 4;        // k-quad
    const int f7 = fr & 7;
    const int bro = (wn & 1) * 64;   // B row offset within its half

    f32x4 acc[8][4];
#pragma unroll
    for (int i = 0; i < 8; ++i)
#pragma unroll
        for (int j = 0; j < 4; ++j) acc[i][j] = (f32x4){0.f, 0.f, 0.f, 0.f};

    const int nk = K / BK;           // 72

    // ---- prologue: tile 0 -> buf0 ----
    stage_half(Abase,                    K, As0,              tid);
    stage_half(Abase + (size_t)128 * K,  K, As0 + HALF_ELEMS, tid);
    stage_half(Bbase,                    K, Bs0,              tid);
    stage_half(Bbase + (size_t)128 * K,  K, Bs0 + HALF_ELEMS, tid);
    asm volatile("s_waitcnt vmcnt(0)" ::: "memory");
    BAR();

    for (int t = 0; t < nk; ++t) {
        const int buf = t & 1;
        __hip_bfloat16* Asb = buf ? As1 : As0;
        __hip_bfloat16* Bsb = buf ? Bs1 : Bs0;
        __hip_bfloat16* Asn = buf ? As0 : As1;   // tile t+1's buffer
        __hip_bfloat16* Bsn = buf ? Bs0 : Bs1;
        const int kb1 = min(t + 1, nk - 1) * BK; // tail: re-stage last tile (never read)

        const __hip_bfloat16* Ah = Asb + wm * HALF_ELEMS;
        const __hip_bfloat16* Bh = Bsb + (wn >> 1) * HALF_ELEMS;

        bf16x8 a[4][2], b0[2][2], b1[2][2];

        // ---- ph0: read A(qr0)+B(qc0); stage A0,A1(t+1); MFMA quad(0,0) ----
        READ_A(0);
        READ_B(b0, 0);
        stage_half(Abase + kb1,                    K, Asn,              tid);
        stage_half(Abase + (size_t)128 * K + kb1,  K, Asn + HALF_ELEMS, tid);
        BAR();
        MFMA_QUAD(0, 0, b0);
        BAR();

        // ---- ph1: read B(qc1); stage B0(t+1); MFMA quad(0,1) ----
        READ_B(b1, 1);
        stage_half(Bbase + kb1, K, Bsn, tid);
        BAR();
        MFMA_QUAD(0, 1, b1);
        BAR();

        // ---- ph2: read A(qr1); stage B1(t+1); MFMA quad(1,1) ----
        READ_A(1);
        stage_half(Bbase + (size_t)128 * K + kb1, K, Bsn + HALF_ELEMS, tid);
        BAR();
        MFMA_QUAD(1, 1, b1);
        BAR();

        // ---- ph3: MFMA quad(1,0) (reuse a + b0); drain; tile-end barrier ----
        MFMA_QUAD(1, 0, b0);
        asm volatile("s_waitcnt vmcnt(0)" ::: "memory");
        BAR();
    }

    // ---- epilogue: C/D mapping col=lane&15, row=(lane>>4)*4+j ----
#pragma unroll
    for (int mi = 0; mi < 8; ++mi) {
        const int r0 = tm * BM + wm * 128 + mi * 16 + kq * 4;
#pragma unroll
        for (int ni = 0; ni < 4; ++ni) {
            const int c = tn * BN + wn * 64 + ni * 16 + fr;
            const float bb = bias[c];
            const f32x4 v = acc[mi][ni];
#pragma unroll
            for (int j = 0; j < 4; ++j)
                C[(size_t)(r0 + j) * N + c] = v[j] + bb;
        }
    }
}

extern "C" void kernel_launch(void* const* d_in, const int* in_sizes, int n_in,
                              void* d_out, int out_size, void* d_ws, size_t ws_size,
                              hipStream_t stream) {
    const float* inp  = (const float*)d_in[0];
    const float* wgt  = (const float*)d_in[1];
    const float* bias = (const float*)d_in[2];
    float* out = (float*)d_out;

    const int N = in_sizes[2];            // 4608
    const int K = in_sizes[1] / N;        // 4608
    const int M = in_sizes[0] / K;        // 8192

    __hip_bfloat16* qA = (__hip_bfloat16*)d_ws;
    __hip_bfloat16* qB = qA + (size_t)M * K;

    const int gA = (int)(((size_t)M * K) / GROUP);
    const int gB = (int)(((size_t)N * K) / GROUP);

    bfp_quant_kernel<<<(gA + 255) / 256, 256, 0, stream>>>(inp, qA, gA);
    bfp_quant_kernel<<<(gB + 255) / 256, 256, 0, stream>>>(wgt, qB, gB);

    const int grid = (M / BM) * (N / BN);            // 32*18 = 576 (mult of 8)
    bfp_gemm_kernel<<<grid, 512, 0, stream>>>(qA, qB, bias, out, M, N, K);
}